// Round 1
// baseline (1602.389 us; speedup 1.0000x reference)
//
#include <hip/hip_runtime.h>

#define NN 50000
#define NE 800000
#define FIN 128
#define H 64
#define NG 64
#define BN_EPS 1e-5f

// ---------------- degree ----------------
__global__ void deg_count(const int* __restrict__ dst, float* __restrict__ deg, int E) {
    int e = blockIdx.x * blockDim.x + threadIdx.x;
    if (e < E) atomicAdd(&deg[dst[e]], 1.0f);
}

__global__ void deg_to_dinv(float* __restrict__ deg, int n) {
    int i = blockIdx.x * blockDim.x + threadIdx.x;
    if (i < n) deg[i] = rsqrtf(deg[i] + 1.0f);
}

// ---------------- h = x @ W^T ----------------
// block = 256 threads = 4 rows x 64 output channels. W cached transposed in LDS.
template <int K>
__global__ void matmul_xwt(const float* __restrict__ x, const float* __restrict__ W,
                           float* __restrict__ out, int n) {
    __shared__ float Ws[K * H];  // Ws[k*H + o] = W[o*K + k]
    for (int i = threadIdx.x; i < H * K; i += 256) {
        int o = i / K, k = i % K;
        Ws[k * H + o] = W[i];
    }
    __syncthreads();
    int row = blockIdx.x * 4 + (threadIdx.x >> 6);
    int o = threadIdx.x & 63;
    if (row >= n) return;
    const float* xr = x + (size_t)row * K;
    float acc = 0.f;
#pragma unroll 4
    for (int k = 0; k < K; ++k) acc += xr[k] * Ws[k * H + o];
    out[(size_t)row * H + o] = acc;
}

// ---------------- agg init: self-loop + bias ----------------
__global__ void self_loop_init(const float* __restrict__ h, const float* __restrict__ dinv,
                               const float* __restrict__ bias, float* __restrict__ agg, int n) {
    int idx = blockIdx.x * blockDim.x + threadIdx.x;
    if (idx >= n * H) return;
    int row = idx >> 6;
    int c = idx & 63;
    float di = dinv[row];
    agg[idx] = h[idx] * di * di + bias[c];
}

// ---------------- edge scatter-add: one edge per 64-lane group ----------------
__global__ void edge_agg(const int* __restrict__ src, const int* __restrict__ dst,
                         const float* __restrict__ dinv, const float* __restrict__ h,
                         float* __restrict__ agg, int E) {
    int e = blockIdx.x * 4 + (threadIdx.x >> 6);
    int c = threadIdx.x & 63;
    if (e >= E) return;
    int s = src[e], d = dst[e];
    float w = dinv[s] * dinv[d];
    atomicAdd(&agg[(size_t)d * H + c], h[(size_t)s * H + c] * w);
}

// ---------------- batchnorm ----------------
__global__ void bn_stats(const float* __restrict__ x, float* __restrict__ sum,
                         float* __restrict__ sumsq, int n) {
    int c = threadIdx.x & 63;
    int rg = threadIdx.x >> 6;  // 0..3
    int base = blockIdx.x * 256;
    float s = 0.f, sq = 0.f;
    for (int r = rg; r < 256; r += 4) {
        int row = base + r;
        if (row < n) {
            float v = x[(size_t)row * H + c];
            s += v;
            sq += v * v;
        }
    }
    __shared__ float ls[256], lq[256];
    ls[threadIdx.x] = s;
    lq[threadIdx.x] = sq;
    __syncthreads();
    if (rg == 0) {
        s = ls[c] + ls[c + 64] + ls[c + 128] + ls[c + 192];
        sq = lq[c] + lq[c + 64] + lq[c + 128] + lq[c + 192];
        atomicAdd(&sum[c], s);
        atomicAdd(&sumsq[c], sq);
    }
}

__global__ void bn_finalize(float* __restrict__ stats, const float* __restrict__ g,
                            const float* __restrict__ be, int n) {
    int c = threadIdx.x;
    if (c >= H) return;
    float mean = stats[c] / (float)n;
    float var = stats[64 + c] / (float)n - mean * mean;
    float sc = g[c] * rsqrtf(var + BN_EPS);
    stats[128 + c] = sc;
    stats[192 + c] = be[c] - mean * sc;
}

__global__ void bn_apply_relu(float* __restrict__ x, const float* __restrict__ stats, int total) {
    int idx = blockIdx.x * blockDim.x + threadIdx.x;
    if (idx >= total) return;
    int c = idx & 63;
    x[idx] = fmaxf(x[idx] * stats[128 + c] + stats[192 + c], 0.0f);
}

// ---------------- global mean pool (sums) ----------------
__global__ void pool_sum(const float* __restrict__ h, const int* __restrict__ batch,
                         float* __restrict__ pool, float* __restrict__ cnt, int n) {
    int row = blockIdx.x * 4 + (threadIdx.x >> 6);
    int c = threadIdx.x & 63;
    if (row >= n) return;
    int g = batch[row];
    atomicAdd(&pool[g * H + c], h[(size_t)row * H + c]);
    if (c == 0) atomicAdd(&cnt[g], 1.0f);
}

// ---------------- final MLP: one thread per graph ----------------
__global__ void final_mlp(const float* __restrict__ pool, const float* __restrict__ cnt,
                          const float* __restrict__ l1w, const float* __restrict__ l1b,
                          const float* __restrict__ l2w, const float* __restrict__ l2b,
                          float* __restrict__ out) {
    int g = threadIdx.x;
    if (g >= NG) return;
    float c = fmaxf(cnt[g], 1.0f);
    float inv = 1.0f / c;
    float p[H];
#pragma unroll
    for (int k = 0; k < H; ++k) p[k] = pool[g * H + k] * inv;
    float acc = l2b[0];
    for (int j = 0; j < 32; ++j) {
        float s = l1b[j];
#pragma unroll
        for (int k = 0; k < H; ++k) s += p[k] * l1w[j * H + k];
        acc += fmaxf(s, 0.0f) * l2w[j];
    }
    out[g] = acc;
}

extern "C" void kernel_launch(void* const* d_in, const int* in_sizes, int n_in,
                              void* d_out, int out_size, void* d_ws, size_t ws_size,
                              hipStream_t stream) {
    const float* x = (const float*)d_in[0];
    const int* ei = (const int*)d_in[1];
    const int* batch = (const int*)d_in[2];
    const float* W[3] = {(const float*)d_in[3], (const float*)d_in[7], (const float*)d_in[11]};
    const float* b[3] = {(const float*)d_in[4], (const float*)d_in[8], (const float*)d_in[12]};
    const float* g[3] = {(const float*)d_in[5], (const float*)d_in[9], (const float*)d_in[13]};
    const float* be[3] = {(const float*)d_in[6], (const float*)d_in[10], (const float*)d_in[14]};
    const float* l1w = (const float*)d_in[15];
    const float* l1b = (const float*)d_in[16];
    const float* l2w = (const float*)d_in[17];
    const float* l2b = (const float*)d_in[18];
    float* out = (float*)d_out;

    const int* src = ei;
    const int* dst = ei + NE;

    float* ws = (float*)d_ws;
    float* dinv = ws;                  // NN (rounded to 50048)
    float* bufA = dinv + 50048;        // NN*H
    float* bufB = bufA + (size_t)NN * H;  // NN*H
    float* stats = bufB + (size_t)NN * H; // 256: sum | sumsq | scale | shift
    float* pool = stats + 256;         // NG*H
    float* cnt = pool + NG * H;        // NG

    // degree -> dinv (in place)
    hipMemsetAsync(dinv, 0, NN * sizeof(float), stream);
    deg_count<<<(NE + 255) / 256, 256, 0, stream>>>(dst, dinv, NE);
    deg_to_dinv<<<(NN + 255) / 256, 256, 0, stream>>>(dinv, NN);

    const int grid_rows = (NN + 3) / 4;       // 12500
    const int grid_elem = (NN * H + 255) / 256;  // 12500
    const int grid_edge = (NE + 3) / 4;       // 200000

    // ---- layer 0 (K=128), input x -> bufB
    matmul_xwt<FIN><<<grid_rows, 256, 0, stream>>>(x, W[0], bufA, NN);
    self_loop_init<<<grid_elem, 256, 0, stream>>>(bufA, dinv, b[0], bufB, NN);
    edge_agg<<<grid_edge, 256, 0, stream>>>(src, dst, dinv, bufA, bufB, NE);
    hipMemsetAsync(stats, 0, 128 * sizeof(float), stream);
    bn_stats<<<196, 256, 0, stream>>>(bufB, stats, stats + 64, NN);
    bn_finalize<<<1, 64, 0, stream>>>(stats, g[0], be[0], NN);
    bn_apply_relu<<<grid_elem, 256, 0, stream>>>(bufB, stats, NN * H);

    // ---- layer 1 (K=64), input bufB -> bufB (via bufA)
    matmul_xwt<H><<<grid_rows, 256, 0, stream>>>(bufB, W[1], bufA, NN);
    self_loop_init<<<grid_elem, 256, 0, stream>>>(bufA, dinv, b[1], bufB, NN);
    edge_agg<<<grid_edge, 256, 0, stream>>>(src, dst, dinv, bufA, bufB, NE);
    hipMemsetAsync(stats, 0, 128 * sizeof(float), stream);
    bn_stats<<<196, 256, 0, stream>>>(bufB, stats, stats + 64, NN);
    bn_finalize<<<1, 64, 0, stream>>>(stats, g[1], be[1], NN);
    bn_apply_relu<<<grid_elem, 256, 0, stream>>>(bufB, stats, NN * H);

    // ---- layer 2 (K=64), input bufB -> bufB (via bufA)
    matmul_xwt<H><<<grid_rows, 256, 0, stream>>>(bufB, W[2], bufA, NN);
    self_loop_init<<<grid_elem, 256, 0, stream>>>(bufA, dinv, b[2], bufB, NN);
    edge_agg<<<grid_edge, 256, 0, stream>>>(src, dst, dinv, bufA, bufB, NE);
    hipMemsetAsync(stats, 0, 128 * sizeof(float), stream);
    bn_stats<<<196, 256, 0, stream>>>(bufB, stats, stats + 64, NN);
    bn_finalize<<<1, 64, 0, stream>>>(stats, g[2], be[2], NN);
    bn_apply_relu<<<grid_elem, 256, 0, stream>>>(bufB, stats, NN * H);

    // ---- global mean pool + MLP head
    hipMemsetAsync(pool, 0, (NG * H + NG) * sizeof(float), stream);
    pool_sum<<<grid_rows, 256, 0, stream>>>(bufB, batch, pool, cnt, NN);
    final_mlp<<<1, 64, 0, stream>>>(pool, cnt, l1w, l1b, l2w, l2b, out);
}

// Round 2
// 989.374 us; speedup vs baseline: 1.6196x; 1.6196x over previous
//
#include <hip/hip_runtime.h>

#define NN 50000
#define NE 800000
#define FIN 128
#define H 64
#define NG 64
#define BN_EPS 1e-5f
#define NB_SCAN 196  // ceil(NN/256)

// ---------------- degree histogram (int) ----------------
__global__ void deg_count(const int* __restrict__ dst, int* __restrict__ deg, int E) {
    int e = blockIdx.x * blockDim.x + threadIdx.x;
    if (e < E) atomicAdd(&deg[dst[e]], 1);
}

__global__ void deg_to_dinv(const int* __restrict__ deg, float* __restrict__ dinv, int n) {
    int i = blockIdx.x * blockDim.x + threadIdx.x;
    if (i < n) dinv[i] = rsqrtf((float)deg[i] + 1.0f);
}

// ---------------- prefix sum (exclusive) over deg -> row_start ----------------
__global__ void scan_block(const int* __restrict__ deg, int* __restrict__ row_start,
                           int* __restrict__ aux, int n) {
    __shared__ int s[256];
    int i = blockIdx.x * 256 + threadIdx.x;
    int v = (i < n) ? deg[i] : 0;
    s[threadIdx.x] = v;
    __syncthreads();
    for (int off = 1; off < 256; off <<= 1) {
        int t = (threadIdx.x >= off) ? s[threadIdx.x - off] : 0;
        __syncthreads();
        s[threadIdx.x] += t;
        __syncthreads();
    }
    if (i < n) row_start[i] = s[threadIdx.x] - v;  // exclusive
    if (threadIdx.x == 255) aux[blockIdx.x] = s[255];
}

__global__ void scan_aux(int* __restrict__ aux, int nb) {
    __shared__ int s[256];
    int v = (threadIdx.x < nb) ? aux[threadIdx.x] : 0;
    s[threadIdx.x] = v;
    __syncthreads();
    for (int off = 1; off < 256; off <<= 1) {
        int t = (threadIdx.x >= off) ? s[threadIdx.x - off] : 0;
        __syncthreads();
        s[threadIdx.x] += t;
        __syncthreads();
    }
    if (threadIdx.x < nb) aux[threadIdx.x] = s[threadIdx.x] - v;  // exclusive
}

__global__ void scan_fixup(int* __restrict__ row_start, const int* __restrict__ aux,
                           int* __restrict__ cursor, int n, int E) {
    int i = blockIdx.x * 256 + threadIdx.x;
    if (i < n) {
        int rs = row_start[i] + aux[i >> 8];
        row_start[i] = rs;
        cursor[i] = rs;
    }
    if (i == 0) row_start[n] = E;
}

// ---------------- scatter edges into CSR (by dst), precompute weights ----------------
__global__ void csr_scatter(const int* __restrict__ src, const int* __restrict__ dst,
                            const float* __restrict__ dinv, int* __restrict__ cursor,
                            int* __restrict__ csr_src, float* __restrict__ csr_w, int E) {
    int e = blockIdx.x * blockDim.x + threadIdx.x;
    if (e >= E) return;
    int s = src[e], d = dst[e];
    int j = atomicAdd(&cursor[d], 1);
    csr_src[j] = s;
    csr_w[j] = dinv[s] * dinv[d];
}

// ---------------- h = x @ W^T ----------------
// block = 256 threads = 4 rows x 64 output channels. W cached transposed in LDS.
template <int K>
__global__ void matmul_xwt(const float* __restrict__ x, const float* __restrict__ W,
                           float* __restrict__ out, int n) {
    __shared__ float Ws[K * H];  // Ws[k*H + o] = W[o*K + k]
    for (int i = threadIdx.x; i < H * K; i += 256) {
        int o = i / K, k = i % K;
        Ws[k * H + o] = W[i];
    }
    __syncthreads();
    int row = blockIdx.x * 4 + (threadIdx.x >> 6);
    int o = threadIdx.x & 63;
    if (row >= n) return;
    const float* xr = x + (size_t)row * K;
    float acc = 0.f;
#pragma unroll 4
    for (int k = 0; k < K; ++k) acc += xr[k] * Ws[k * H + o];
    out[(size_t)row * H + o] = acc;
}

// ---------------- fused GCN aggregation: gather over CSR + self-loop + bias ----------------
__global__ void gcn_gather(const float* __restrict__ h, const int* __restrict__ row_start,
                           const int* __restrict__ csr_src, const float* __restrict__ csr_w,
                           const float* __restrict__ dinv, const float* __restrict__ bias,
                           float* __restrict__ out, int n) {
    int d = blockIdx.x * 4 + (threadIdx.x >> 6);
    int c = threadIdx.x & 63;
    if (d >= n) return;
    float di = dinv[d];
    float acc = h[(size_t)d * H + c] * di * di + bias[c];
    int j0 = row_start[d], j1 = row_start[d + 1];
    for (int j = j0; j < j1; ++j) {
        int s = csr_src[j];
        float w = csr_w[j];
        acc += h[(size_t)s * H + c] * w;
    }
    out[(size_t)d * H + c] = acc;
}

// ---------------- batchnorm ----------------
__global__ void bn_stats(const float* __restrict__ x, float* __restrict__ sum,
                         float* __restrict__ sumsq, int n) {
    int c = threadIdx.x & 63;
    int rg = threadIdx.x >> 6;  // 0..3
    int base = blockIdx.x * 256;
    float s = 0.f, sq = 0.f;
    for (int r = rg; r < 256; r += 4) {
        int row = base + r;
        if (row < n) {
            float v = x[(size_t)row * H + c];
            s += v;
            sq += v * v;
        }
    }
    __shared__ float ls[256], lq[256];
    ls[threadIdx.x] = s;
    lq[threadIdx.x] = sq;
    __syncthreads();
    if (rg == 0) {
        s = ls[c] + ls[c + 64] + ls[c + 128] + ls[c + 192];
        sq = lq[c] + lq[c + 64] + lq[c + 128] + lq[c + 192];
        atomicAdd(&sum[c], s);
        atomicAdd(&sumsq[c], sq);
    }
}

__global__ void bn_finalize(float* __restrict__ stats, const float* __restrict__ g,
                            const float* __restrict__ be, int n) {
    int c = threadIdx.x;
    if (c >= H) return;
    float mean = stats[c] / (float)n;
    float var = stats[64 + c] / (float)n - mean * mean;
    float sc = g[c] * rsqrtf(var + BN_EPS);
    stats[128 + c] = sc;
    stats[192 + c] = be[c] - mean * sc;
}

__global__ void bn_apply_relu(float* __restrict__ x, const float* __restrict__ stats, int total) {
    int idx = blockIdx.x * blockDim.x + threadIdx.x;
    if (idx >= total) return;
    int c = idx & 63;
    x[idx] = fmaxf(x[idx] * stats[128 + c] + stats[192 + c], 0.0f);
}

// ---------------- global mean pool: segmented reduction (batch is sorted) ----------------
#define PROWS 128
__global__ void pool_seg(const float* __restrict__ h, const int* __restrict__ batch,
                         float* __restrict__ pool, float* __restrict__ cnt, int n) {
    int wave = blockIdx.x * 4 + (threadIdx.x >> 6);
    int c = threadIdx.x & 63;
    int r0 = wave * PROWS;
    if (r0 >= n) return;
    int r1 = min(r0 + PROWS, n);
    int cur = batch[r0];
    float acc = 0.f;
    int nlocal = 0;
    for (int r = r0; r < r1; ++r) {
        int g = batch[r];
        if (g != cur) {
            atomicAdd(&pool[cur * H + c], acc);
            if (c == 0) atomicAdd(&cnt[cur], (float)nlocal);
            cur = g;
            acc = 0.f;
            nlocal = 0;
        }
        acc += h[(size_t)r * H + c];
        ++nlocal;
    }
    atomicAdd(&pool[cur * H + c], acc);
    if (c == 0) atomicAdd(&cnt[cur], (float)nlocal);
}

// ---------------- final MLP: one thread per graph ----------------
__global__ void final_mlp(const float* __restrict__ pool, const float* __restrict__ cnt,
                          const float* __restrict__ l1w, const float* __restrict__ l1b,
                          const float* __restrict__ l2w, const float* __restrict__ l2b,
                          float* __restrict__ out) {
    int g = threadIdx.x;
    if (g >= NG) return;
    float c = fmaxf(cnt[g], 1.0f);
    float inv = 1.0f / c;
    float p[H];
#pragma unroll
    for (int k = 0; k < H; ++k) p[k] = pool[g * H + k] * inv;
    float acc = l2b[0];
    for (int j = 0; j < 32; ++j) {
        float s = l1b[j];
#pragma unroll
        for (int k = 0; k < H; ++k) s += p[k] * l1w[j * H + k];
        acc += fmaxf(s, 0.0f) * l2w[j];
    }
    out[g] = acc;
}

extern "C" void kernel_launch(void* const* d_in, const int* in_sizes, int n_in,
                              void* d_out, int out_size, void* d_ws, size_t ws_size,
                              hipStream_t stream) {
    const float* x = (const float*)d_in[0];
    const int* ei = (const int*)d_in[1];
    const int* batch = (const int*)d_in[2];
    const float* W[3] = {(const float*)d_in[3], (const float*)d_in[7], (const float*)d_in[11]};
    const float* b[3] = {(const float*)d_in[4], (const float*)d_in[8], (const float*)d_in[12]};
    const float* g[3] = {(const float*)d_in[5], (const float*)d_in[9], (const float*)d_in[13]};
    const float* be[3] = {(const float*)d_in[6], (const float*)d_in[10], (const float*)d_in[14]};
    const float* l1w = (const float*)d_in[15];
    const float* l1b = (const float*)d_in[16];
    const float* l2w = (const float*)d_in[17];
    const float* l2b = (const float*)d_in[18];
    float* out = (float*)d_out;

    const int* src = ei;
    const int* dst = ei + NE;

    // ---- workspace layout (4-byte units) ----
    char* wsb = (char*)d_ws;
    size_t off = 0;
    auto alloc = [&](size_t elems) {
        void* p = wsb + off;
        off += elems * 4;
        return p;
    };
    float* dinv = (float*)alloc(50048);
    float* bufA = (float*)alloc((size_t)NN * H);
    float* bufB = (float*)alloc((size_t)NN * H);
    float* stats = (float*)alloc(256);   // sum | sumsq | scale | shift
    float* pool = (float*)alloc(NG * H);
    float* cnt = (float*)alloc(64);
    int* deg = (int*)alloc(50048);
    int* row_start = (int*)alloc(50112);  // NN+1
    int* aux = (int*)alloc(256);
    int* cursor = (int*)alloc(50048);
    int* csr_src = (int*)alloc(NE);
    float* csr_w = (float*)alloc(NE);

    // ---- build dinv + CSR (by dst) ----
    hipMemsetAsync(deg, 0, NN * sizeof(int), stream);
    deg_count<<<(NE + 255) / 256, 256, 0, stream>>>(dst, deg, NE);
    deg_to_dinv<<<(NN + 255) / 256, 256, 0, stream>>>(deg, dinv, NN);
    scan_block<<<NB_SCAN, 256, 0, stream>>>(deg, row_start, aux, NN);
    scan_aux<<<1, 256, 0, stream>>>(aux, NB_SCAN);
    scan_fixup<<<NB_SCAN, 256, 0, stream>>>(row_start, aux, cursor, NN, NE);
    csr_scatter<<<(NE + 255) / 256, 256, 0, stream>>>(src, dst, dinv, cursor, csr_src, csr_w, NE);

    const int grid_rows = (NN + 3) / 4;          // 12500
    const int grid_elem = (NN * H + 255) / 256;  // 12500

    // ---- 3 GCN layers ----
    for (int L = 0; L < 3; ++L) {
        if (L == 0)
            matmul_xwt<FIN><<<grid_rows, 256, 0, stream>>>(x, W[0], bufA, NN);
        else
            matmul_xwt<H><<<grid_rows, 256, 0, stream>>>(bufB, W[L], bufA, NN);
        gcn_gather<<<grid_rows, 256, 0, stream>>>(bufA, row_start, csr_src, csr_w, dinv, b[L],
                                                  bufB, NN);
        hipMemsetAsync(stats, 0, 128 * sizeof(float), stream);
        bn_stats<<<196, 256, 0, stream>>>(bufB, stats, stats + 64, NN);
        bn_finalize<<<1, 64, 0, stream>>>(stats, g[L], be[L], NN);
        bn_apply_relu<<<grid_elem, 256, 0, stream>>>(bufB, stats, NN * H);
    }

    // ---- global mean pool + MLP head ----
    hipMemsetAsync(pool, 0, (NG * H + NG) * sizeof(float), stream);
    pool_seg<<<(((NN + PROWS - 1) / PROWS) + 3) / 4, 256, 0, stream>>>(bufB, batch, pool, cnt, NN);
    final_mlp<<<1, 64, 0, stream>>>(pool, cnt, l1w, l1b, l2w, l2b, out);
}